// Round 1
// baseline (24818.909 us; speedup 1.0000x reference)
//
#include <hip/hip_runtime.h>

// BasicMGU: h-recurrence over T=1024 steps.
// Structure: 4 batch-groups x 16 rows; 16 WGs per group, each owns 32 output cols.
// Weights as register-resident bf16 hi/lo fragments (3-MFMA split => ~fp21 precision).
// h and g=h*f exchanged through d_ws as bf16 hi/lo pairs; 2 device-scope group
// barriers per step. 64 WGs x 256 threads, 1 WG/CU (co-resident, no deadlock).

typedef __bf16 bf16;
typedef __attribute__((ext_vector_type(8))) __bf16 bf16x8;
typedef __attribute__((ext_vector_type(4))) float f32x4;

#define MFMA16(a, b, c) __builtin_amdgcn_mfma_f32_16x16x32_bf16((a), (b), (c), 0, 0, 0)

constexpr int Bc = 64, Tc = 1024, Dc = 512, Uc = 512;
constexpr int GROUPS = 4, ROWS = 16, WPG = 16, NCOL = 32;

// ws layout (bytes):
//   [0,1024):            4 group barrier counters, 256B apart
//   [4096  , +65536):    h_hi  [4][16][512] bf16
//   [69632 , +65536):    h_lo
//   [135168, +65536):    g_hi
//   [200704, +65536):    g_lo
constexpr size_t WS_HH = 4096;
constexpr size_t WS_HL = 4096 + 65536;
constexpr size_t WS_GH = 4096 + 2 * 65536;
constexpr size_t WS_GL = 4096 + 3 * 65536;
constexpr size_t WS_ZERO_BYTES = 4096 + 4 * 65536;  // 266240

__device__ inline void group_barrier(unsigned* ctr, unsigned target) {
  __threadfence();      // release our g/h stores to device scope
  __syncthreads();
  if (threadIdx.x == 0) {
    __hip_atomic_fetch_add(ctr, 1u, __ATOMIC_RELEASE, __HIP_MEMORY_SCOPE_AGENT);
    while (__hip_atomic_load(ctr, __ATOMIC_RELAXED, __HIP_MEMORY_SCOPE_AGENT) < target)
      __builtin_amdgcn_s_sleep(1);
  }
  __syncthreads();
  __builtin_amdgcn_fence(__ATOMIC_ACQUIRE, "agent");  // invalidate L1 before reading peers' data
}

__global__ __launch_bounds__(256, 1)
void mgu_kernel(const float* __restrict__ x,
                const float* __restrict__ Wk, const float* __restrict__ Wr,
                const float* __restrict__ br,
                const float* __restrict__ Wu, const float* __restrict__ Wur,
                const float* __restrict__ bur,
                bf16* __restrict__ hh, bf16* __restrict__ hl,
                bf16* __restrict__ gh, bf16* __restrict__ gl,
                unsigned* __restrict__ ctrs, float* __restrict__ out) {
  __shared__ float red[2][16][16];

  const int wg = blockIdx.x;
  const int g = wg >> 4;          // batch group 0..3
  const int cw = wg & 15;         // column-slice WG within group
  const int c0 = cw * NCOL;
  const int tid = threadIdx.x;
  const int w = tid >> 6, lane = tid & 63;
  const int ct = w >> 1;          // column tile (16 cols) 0/1
  const int kh = w & 1;           // K half 0/1 (256 each)
  const int r16 = lane & 15;      // frag row (A) / col (B,D)
  const int kq = lane >> 4;       // k quarter within 32-chunk
  const int col = c0 + ct * 16 + r16;      // this lane's output column
  const int kwbase = kh * 256 + kq * 8;    // lane's k base within its half

  // ---- one-time: weight fragments (hi/lo split) into registers.
  // B-frag layout: lane holds W[k = kwbase + kb*32 + j][col], j=0..7.
  bf16x8 wfhi[4][8], wflo[4][8];
  {
#pragma unroll
    for (int m = 0; m < 4; ++m) {
      const float* W = (m == 0) ? Wk : (m == 1) ? Wr : (m == 2) ? Wu : Wur;
#pragma unroll
      for (int kb = 0; kb < 8; ++kb) {
#pragma unroll
        for (int j = 0; j < 8; ++j) {
          float v = W[(size_t)(kwbase + kb * 32 + j) * Uc + col];
          bf16 hi = (bf16)v;
          wfhi[m][kb][j] = hi;
          wflo[m][kb][j] = (bf16)(v - (float)hi);
        }
      }
    }
  }

  const float brv = br[col], burv = bur[col];

  bf16* hhg = hh + g * ROWS * Uc;
  bf16* hlg = hl + g * ROWS * Uc;
  bf16* ghg = gh + g * ROWS * Uc;
  bf16* glg = gl + g * ROWS * Uc;
  unsigned* ctr = ctrs + g * 64;  // 256B apart
  unsigned bar = 0;

  const float* xrow = x + (size_t)(g * ROWS + r16) * Tc * Dc;

  float h_keep[4] = {0.f, 0.f, 0.f, 0.f};  // kh==0 waves: own h values at (kq*4+r, col)
  float f_keep[4];

  for (int t = 0; t < Tc; ++t) {
    // ---- x_t A-fragments for our K half (hi/lo split), reused by both phases
    bf16x8 xhi[8], xlo[8];
    const float* xp = xrow + (size_t)t * Dc + kwbase;
#pragma unroll
    for (int kb = 0; kb < 8; ++kb) {
      f32x4 a = *(const f32x4*)(xp + kb * 32);
      f32x4 b = *(const f32x4*)(xp + kb * 32 + 4);
#pragma unroll
      for (int j = 0; j < 4; ++j) {
        bf16 h0 = (bf16)a[j];
        xhi[kb][j] = h0;
        xlo[kb][j] = (bf16)(a[j] - (float)h0);
        bf16 h1 = (bf16)b[j];
        xhi[kb][4 + j] = h1;
        xlo[kb][4 + j] = (bf16)(b[j] - (float)h1);
      }
    }

    // ---- phase 1: a_f = x_t@Wk + h@Wr   (our 16-col tile, our K half)
    f32x4 p0 = {0, 0, 0, 0}, p1 = {0, 0, 0, 0}, p2 = {0, 0, 0, 0};
    f32x4 p3 = {0, 0, 0, 0}, p4 = {0, 0, 0, 0}, p5 = {0, 0, 0, 0};
#pragma unroll
    for (int kb = 0; kb < 8; ++kb) {
      const int kidx = kwbase + kb * 32;
      bf16x8 hfh = *(const bf16x8*)(hhg + r16 * Uc + kidx);
      bf16x8 hfl = *(const bf16x8*)(hlg + r16 * Uc + kidx);
      p0 = MFMA16(xhi[kb], wfhi[0][kb], p0);
      p1 = MFMA16(xlo[kb], wfhi[0][kb], p1);
      p2 = MFMA16(xhi[kb], wflo[0][kb], p2);
      p3 = MFMA16(hfh, wfhi[1][kb], p3);
      p4 = MFMA16(hfl, wfhi[1][kb], p4);
      p5 = MFMA16(hfh, wflo[1][kb], p5);
    }
    if (kh == 1) {
#pragma unroll
      for (int r = 0; r < 4; ++r)
        red[ct][kq * 4 + r][r16] = p0[r] + p1[r] + p2[r] + p3[r] + p4[r] + p5[r];
    }
    __syncthreads();
    if (kh == 0) {
#pragma unroll
      for (int r = 0; r < 4; ++r) {
        float af = p0[r] + p1[r] + p2[r] + p3[r] + p4[r] + p5[r] +
                   red[ct][kq * 4 + r][r16] + brv;
        float f = 1.f / (1.f + __expf(-af));
        float gv = h_keep[r] * f;
        bf16 ghi = (bf16)gv;
        const int row = kq * 4 + r;
        ghg[row * Uc + col] = ghi;
        glg[row * Uc + col] = (bf16)(gv - (float)ghi);
        f_keep[r] = f;
      }
    }
    group_barrier(ctr, (++bar) * WPG);  // publish g = h.*f

    // ---- phase 2: a_h = x_t@Wu + g@Wur
    f32x4 q0 = {0, 0, 0, 0}, q1 = {0, 0, 0, 0}, q2 = {0, 0, 0, 0};
    f32x4 q3 = {0, 0, 0, 0}, q4 = {0, 0, 0, 0}, q5 = {0, 0, 0, 0};
#pragma unroll
    for (int kb = 0; kb < 8; ++kb) {
      const int kidx = kwbase + kb * 32;
      bf16x8 gfh = *(const bf16x8*)(ghg + r16 * Uc + kidx);
      bf16x8 gfl = *(const bf16x8*)(glg + r16 * Uc + kidx);
      q0 = MFMA16(xhi[kb], wfhi[2][kb], q0);
      q1 = MFMA16(xlo[kb], wfhi[2][kb], q1);
      q2 = MFMA16(xhi[kb], wflo[2][kb], q2);
      q3 = MFMA16(gfh, wfhi[3][kb], q3);
      q4 = MFMA16(gfl, wfhi[3][kb], q4);
      q5 = MFMA16(gfh, wflo[3][kb], q5);
    }
    if (kh == 1) {
#pragma unroll
      for (int r = 0; r < 4; ++r)
        red[ct][kq * 4 + r][r16] = q0[r] + q1[r] + q2[r] + q3[r] + q4[r] + q5[r];
    }
    __syncthreads();
    if (kh == 0) {
#pragma unroll
      for (int r = 0; r < 4; ++r) {
        float ah = q0[r] + q1[r] + q2[r] + q3[r] + q4[r] + q5[r] +
                   red[ct][kq * 4 + r][r16] + burv;
        float hc = tanhf(ah);
        float hn = h_keep[r] + f_keep[r] * (hc - h_keep[r]);
        const int row = kq * 4 + r;
        bf16 nh = (bf16)hn;
        hhg[row * Uc + col] = nh;
        hlg[row * Uc + col] = (bf16)(hn - (float)nh);
        h_keep[r] = hn;
        if (t == Tc - 1) out[(size_t)(g * ROWS + row) * Uc + col] = hn;
      }
    }
    group_barrier(ctr, (++bar) * WPG);  // publish h_{t+1}
  }
}

extern "C" void kernel_launch(void* const* d_in, const int* in_sizes, int n_in,
                              void* d_out, int out_size, void* d_ws, size_t ws_size,
                              hipStream_t stream) {
  const float* x   = (const float*)d_in[0];
  const float* Wk  = (const float*)d_in[1];
  const float* Wr  = (const float*)d_in[2];
  const float* br  = (const float*)d_in[3];
  const float* Wu  = (const float*)d_in[4];
  const float* Wur = (const float*)d_in[5];
  const float* bur = (const float*)d_in[6];
  float* out = (float*)d_out;

  char* ws = (char*)d_ws;
  unsigned* ctrs = (unsigned*)ws;
  bf16* hh = (bf16*)(ws + WS_HH);
  bf16* hl = (bf16*)(ws + WS_HL);
  bf16* gh = (bf16*)(ws + WS_GH);
  bf16* gl = (bf16*)(ws + WS_GL);

  // zero h0, g, and barrier counters (deterministic per call)
  hipMemsetAsync(d_ws, 0, WS_ZERO_BYTES, stream);

  hipLaunchKernelGGL(mgu_kernel, dim3(GROUPS * WPG), dim3(256), 0, stream,
                     x, Wk, Wr, br, Wu, Wur, bur, hh, hl, gh, gl, ctrs, out);
}

// Round 2
// 23815.593 us; speedup vs baseline: 1.0421x; 1.0421x over previous
//
#include <hip/hip_runtime.h>

// BasicMGU scan: 4 batch-groups x 16 rows; 16 WGs/group each owning 32 cols.
// Cross-WG h/g exchange via agent-scope RELAXED atomics (sc0 sc1 -> Infinity
// Cache coherence point). No cache-wide fences: ordering = s_waitcnt vmcnt(0)
// + counter add; consumers spin then sc1-load. L1/L2 stay warm for x/weights.
// All h-independent work (x convert + x@Wk + x@Wu MFMAs) runs inside the
// barrier-B wait window of the previous step.

typedef __bf16 bf16;
typedef __attribute__((ext_vector_type(8))) __bf16 bf16x8;
typedef __attribute__((ext_vector_type(4))) float f32x4;

#define MFMA16(a, b, c) __builtin_amdgcn_mfma_f32_16x16x32_bf16((a), (b), (c), 0, 0, 0)

constexpr int Tc = 1024, Dc = 512, Uc = 512;
constexpr int GROUPS = 4, ROWS = 16, WPG = 16;
constexpr unsigned GW = 64;  // arriving waves per group (16 WGs x 4 waves)

// ws layout: [0,1024): 4 counters 256B apart; then hx[4][16][512] u32; gx same.
constexpr size_t WS_H = 4096;
constexpr size_t WS_G = 4096 + (size_t)GROUPS * ROWS * Uc * 4;
constexpr size_t WS_ZERO_BYTES = 4096 + (size_t)2 * GROUPS * ROWS * Uc * 4;  // 266240

// pack hi/lo bf16 split of v into one dword (hi in [15:0], lo in [31:16])
__device__ inline unsigned pack2(float v) {
  bf16 hi = (bf16)v;
  bf16 lo = (bf16)(v - (float)hi);
  return (unsigned)__builtin_bit_cast(unsigned short, hi) |
         ((unsigned)__builtin_bit_cast(unsigned short, lo) << 16);
}

__device__ inline void unpack8(const unsigned* u, bf16x8& fh, bf16x8& fl) {
  union { unsigned d[4]; bf16x8 v; } H, L;
#pragma unroll
  for (int j = 0; j < 4; ++j) {
    unsigned a = u[2 * j], b = u[2 * j + 1];
    H.d[j] = (a & 0xffffu) | (b << 16);
    L.d[j] = (a >> 16) | (b & 0xffff0000u);
  }
  fh = H.v;
  fl = L.v;
}

__device__ inline void wave_arrive(unsigned* ctr) {
  asm volatile("s_waitcnt vmcnt(0)" ::: "memory");  // h/g sc1 stores ack'd at IF
  if ((threadIdx.x & 63) == 0)
    (void)__hip_atomic_fetch_add(ctr, 1u, __ATOMIC_RELAXED, __HIP_MEMORY_SCOPE_AGENT);
}

__device__ inline void wave_wait(unsigned* ctr, unsigned target) {
  while (__hip_atomic_load(ctr, __ATOMIC_RELAXED, __HIP_MEMORY_SCOPE_AGENT) < target)
    __builtin_amdgcn_s_sleep(1);
  asm volatile("" ::: "memory");
}

__global__ __launch_bounds__(256, 1)
void mgu_kernel(const float* __restrict__ x,
                const float* __restrict__ Wk, const float* __restrict__ Wr,
                const float* __restrict__ br,
                const float* __restrict__ Wu, const float* __restrict__ Wur,
                const float* __restrict__ bur,
                unsigned* __restrict__ hx, unsigned* __restrict__ gx,
                unsigned* __restrict__ ctrs, float* __restrict__ out) {
  __shared__ float red[2][16][16];

  const int wg = blockIdx.x;
  const int g = wg >> 4, cw = wg & 15;
  const int c0 = cw * 32;
  const int tid = threadIdx.x;
  const int w = tid >> 6, lane = tid & 63;
  const int ct = w >> 1, kh = w & 1;
  const int r16 = lane & 15, kq = lane >> 4;
  const int col = c0 + ct * 16 + r16;
  const int kwbase = kh * 256 + kq * 8;

  // ---- one-time: weights into registers. Wr/Wur hi+lo; Wk/Wu hi only.
  bf16x8 wkh_[8], wrh_[8], wrl_[8], wuh_[8], wqh_[8], wql_[8];
#pragma unroll
  for (int kb = 0; kb < 8; ++kb) {
#pragma unroll
    for (int j = 0; j < 8; ++j) {
      const size_t ko = (size_t)(kwbase + kb * 32 + j) * Uc + col;
      { float v = Wk[ko]; wkh_[kb][j] = (bf16)v; }
      { float v = Wr[ko]; bf16 h0 = (bf16)v; wrh_[kb][j] = h0; wrl_[kb][j] = (bf16)(v - (float)h0); }
      { float v = Wu[ko]; wuh_[kb][j] = (bf16)v; }
      { float v = Wur[ko]; bf16 h0 = (bf16)v; wqh_[kb][j] = h0; wql_[kb][j] = (bf16)(v - (float)h0); }
    }
  }

  const float brv = br[col], burv = bur[col];

  unsigned* hxg = hx + g * (ROWS * Uc);
  unsigned* gxg = gx + g * (ROWS * Uc);
  unsigned* hxr = hxg + r16 * Uc;   // load row for A-fragments
  unsigned* gxr = gxg + r16 * Uc;
  unsigned* ctr = ctrs + g * 64;    // 256B apart

  const float* xrow = x + (size_t)(g * ROWS + r16) * Tc * Dc + kwbase;

  float h_keep[4] = {0.f, 0.f, 0.f, 0.f}, f_keep[4];

  bf16x8 xhi[8], xlo[8];
  f32x4 axk0, axk1, axu0, axu1;  // x@Wk and x@Wu partials (done in B window)

  auto do_x = [&](int t) {
    const float* xp = xrow + (size_t)t * Dc;
#pragma unroll
    for (int kb = 0; kb < 8; ++kb) {
      f32x4 a = *(const f32x4*)(xp + kb * 32);
      f32x4 b = *(const f32x4*)(xp + kb * 32 + 4);
#pragma unroll
      for (int j = 0; j < 4; ++j) {
        bf16 h0 = (bf16)a[j]; xhi[kb][j] = h0; xlo[kb][j] = (bf16)(a[j] - (float)h0);
        bf16 h1 = (bf16)b[j]; xhi[kb][4 + j] = h1; xlo[kb][4 + j] = (bf16)(b[j] - (float)h1);
      }
    }
    axk0 = (f32x4){0.f, 0.f, 0.f, 0.f}; axk1 = axk0; axu0 = axk0; axu1 = axk0;
#pragma unroll
    for (int kb = 0; kb < 8; ++kb) {
      axk0 = MFMA16(xhi[kb], wkh_[kb], axk0);
      axk1 = MFMA16(xlo[kb], wkh_[kb], axk1);
      axu0 = MFMA16(xhi[kb], wuh_[kb], axu0);
      axu1 = MFMA16(xlo[kb], wuh_[kb], axu1);
    }
  };

  do_x(0);
  unsigned bar = 0;

  for (int t = 0; t < Tc; ++t) {
    // ---- phase 1: + h @ Wr (hi/lo), h via sc1 loads
    f32x4 r0 = {0.f, 0.f, 0.f, 0.f}, r1 = r0, r2 = r0;
#pragma unroll
    for (int kb = 0; kb < 8; ++kb) {
      unsigned u[8];
#pragma unroll
      for (int j = 0; j < 8; ++j)
        u[j] = __hip_atomic_load(hxr + kwbase + kb * 32 + j,
                                 __ATOMIC_RELAXED, __HIP_MEMORY_SCOPE_AGENT);
      bf16x8 fh, fl;
      unpack8(u, fh, fl);
      r0 = MFMA16(fh, wrh_[kb], r0);
      r1 = MFMA16(fl, wrh_[kb], r1);
      r2 = MFMA16(fh, wrl_[kb], r2);
    }
    if (kh == 1) {
#pragma unroll
      for (int r = 0; r < 4; ++r)
        red[ct][kq * 4 + r][r16] = axk0[r] + axk1[r] + r0[r] + r1[r] + r2[r];
    }
    __syncthreads();
    if (kh == 0) {
#pragma unroll
      for (int r = 0; r < 4; ++r) {
        float af = axk0[r] + axk1[r] + r0[r] + r1[r] + r2[r] +
                   red[ct][kq * 4 + r][r16] + brv;
        float f = __builtin_amdgcn_rcpf(1.f + __expf(-af));
        float gv = h_keep[r] * f;
        f_keep[r] = f;
        __hip_atomic_store(gxg + (kq * 4 + r) * Uc + col, pack2(gv),
                           __ATOMIC_RELAXED, __HIP_MEMORY_SCOPE_AGENT);
      }
    }
    wave_arrive(ctr);
    wave_wait(ctr, (++bar) * GW);  // g published

    // ---- phase 2: + g @ Wur (hi/lo)
    f32x4 q0 = {0.f, 0.f, 0.f, 0.f}, q1 = q0, q2 = q0;
#pragma unroll
    for (int kb = 0; kb < 8; ++kb) {
      unsigned u[8];
#pragma unroll
      for (int j = 0; j < 8; ++j)
        u[j] = __hip_atomic_load(gxr + kwbase + kb * 32 + j,
                                 __ATOMIC_RELAXED, __HIP_MEMORY_SCOPE_AGENT);
      bf16x8 fh, fl;
      unpack8(u, fh, fl);
      q0 = MFMA16(fh, wqh_[kb], q0);
      q1 = MFMA16(fl, wqh_[kb], q1);
      q2 = MFMA16(fh, wql_[kb], q2);
    }
    if (kh == 1) {
#pragma unroll
      for (int r = 0; r < 4; ++r)
        red[ct][kq * 4 + r][r16] = axu0[r] + axu1[r] + q0[r] + q1[r] + q2[r];
    }
    __syncthreads();
    if (kh == 0) {
#pragma unroll
      for (int r = 0; r < 4; ++r) {
        float ah = axu0[r] + axu1[r] + q0[r] + q1[r] + q2[r] +
                   red[ct][kq * 4 + r][r16] + burv;
        float e2 = __expf(2.f * ah);
        float hc = 1.f - 2.f * __builtin_amdgcn_rcpf(e2 + 1.f);  // tanh, NaN-safe
        float hn = h_keep[r] + f_keep[r] * (hc - h_keep[r]);
        h_keep[r] = hn;
        __hip_atomic_store(hxg + (kq * 4 + r) * Uc + col, pack2(hn),
                           __ATOMIC_RELAXED, __HIP_MEMORY_SCOPE_AGENT);
        if (t == Tc - 1) out[(size_t)(g * ROWS + kq * 4 + r) * Uc + col] = hn;
      }
    }
    wave_arrive(ctr);
    if (t + 1 < Tc) do_x(t + 1);   // overlap x(t+1) work with barrier wait
    wave_wait(ctr, (++bar) * GW);  // h published
  }
}

extern "C" void kernel_launch(void* const* d_in, const int* in_sizes, int n_in,
                              void* d_out, int out_size, void* d_ws, size_t ws_size,
                              hipStream_t stream) {
  const float* x   = (const float*)d_in[0];
  const float* Wk  = (const float*)d_in[1];
  const float* Wr  = (const float*)d_in[2];
  const float* br  = (const float*)d_in[3];
  const float* Wu  = (const float*)d_in[4];
  const float* Wur = (const float*)d_in[5];
  const float* bur = (const float*)d_in[6];
  float* out = (float*)d_out;

  char* ws = (char*)d_ws;
  unsigned* ctrs = (unsigned*)ws;
  unsigned* hx = (unsigned*)(ws + WS_H);
  unsigned* gx = (unsigned*)(ws + WS_G);

  hipMemsetAsync(d_ws, 0, WS_ZERO_BYTES, stream);  // h0 = 0, counters = 0

  hipLaunchKernelGGL(mgu_kernel, dim3(GROUPS * WPG), dim3(256), 0, stream,
                     x, Wk, Wr, br, Wu, Wur, bur, hx, gx, ctrs, out);
}

// Round 3
// 12819.470 us; speedup vs baseline: 1.9360x; 1.8578x over previous
//
#include <hip/hip_runtime.h>

// BasicMGU scan. 4 batch-groups x 16 rows; 16 WGs/group each owning 32 cols.
// Exchange h/g via IF-coherent (sc0 sc1) loads/stores. Barrier = per-wave
// epoch flag stores (NO atomic RMW) + 64-slot ballot poll (busy, no s_sleep).
// Weights pinned in VGPRs via opaque asm keep (defeats remat/reload).

typedef __bf16 bf16;
typedef __attribute__((ext_vector_type(8))) __bf16 bf16x8;
typedef __attribute__((ext_vector_type(4))) float f32x4;
typedef __attribute__((ext_vector_type(4))) unsigned u32x4;

#define MFMA16(a, b, c) __builtin_amdgcn_mfma_f32_16x16x32_bf16((a), (b), (c), 0, 0, 0)

constexpr int Tc = 1024, Dc = 512, Uc = 512;
constexpr int GROUPS = 4, ROWS = 16, WPG = 16;

// ws layout: flags[4][64] u32 (256B per group) at 0; hx[4][16][512] u32; gx same.
constexpr size_t WS_H = 4096;
constexpr size_t WS_G = WS_H + (size_t)GROUPS * ROWS * Uc * 4;
constexpr size_t WS_ZERO_BYTES = WS_G + (size_t)GROUPS * ROWS * Uc * 4;  // 266240

__device__ inline unsigned pack2(float v) {
  bf16 hi = (bf16)v;
  bf16 lo = (bf16)(v - (float)hi);
  return (unsigned)__builtin_bit_cast(unsigned short, hi) |
         ((unsigned)__builtin_bit_cast(unsigned short, lo) << 16);
}

__device__ inline void unpack8(u32x4 A, u32x4 B, bf16x8& fh, bf16x8& fl) {
  union { unsigned d[4]; bf16x8 v; } H, L;
  unsigned u[8] = {A[0], A[1], A[2], A[3], B[0], B[1], B[2], B[3]};
#pragma unroll
  for (int j = 0; j < 4; ++j) {
    unsigned a = u[2 * j], b = u[2 * j + 1];
    H.d[j] = (a & 0xffffu) | (b << 16);
    L.d[j] = (a >> 16) | (b & 0xffff0000u);
  }
  fh = H.v;
  fl = L.v;
}

// two dwordx4 coherent loads (32B): bypass L1/L2, served at IF (always fresh)
__device__ inline void load8(const unsigned* p, u32x4& a, u32x4& b) {
  asm volatile("global_load_dwordx4 %0, %2, off sc0 sc1\n\t"
               "global_load_dwordx4 %1, %2, off offset:16 sc0 sc1"
               : "=v"(a), "=v"(b) : "v"(p) : "memory");
}

__device__ inline void arrive(unsigned* flags, int slot, unsigned e) {
  asm volatile("s_waitcnt vmcnt(0)" ::: "memory");  // our data stores ack'd at IF
  if ((threadIdx.x & 63) == 0)
    __hip_atomic_store(flags + slot, e, __ATOMIC_RELAXED, __HIP_MEMORY_SCOPE_AGENT);
}

__device__ inline void waitall(unsigned* flags, int lane, unsigned e) {
  for (;;) {
    unsigned v = __hip_atomic_load(flags + lane, __ATOMIC_RELAXED, __HIP_MEMORY_SCOPE_AGENT);
    if (__ballot(v >= e) == ~0ull) break;
  }
  asm volatile("" ::: "memory");
}

__global__ __launch_bounds__(256, 1)
void mgu_kernel(const float* __restrict__ x,
                const float* __restrict__ Wk, const float* __restrict__ Wr,
                const float* __restrict__ br,
                const float* __restrict__ Wu, const float* __restrict__ Wur,
                const float* __restrict__ bur,
                unsigned* __restrict__ hx, unsigned* __restrict__ gx,
                unsigned* __restrict__ ctrs, float* __restrict__ out) {
  __shared__ float red[2][16][16];

  const int wg = blockIdx.x;
  const int g = wg >> 4, cw = wg & 15;
  const int c0 = cw * 32;
  const int tid = threadIdx.x;
  const int w = tid >> 6, lane = tid & 63;
  const int ct = w >> 1, kh = w & 1;
  const int r16 = lane & 15, kq = lane >> 4;
  const int col = c0 + ct * 16 + r16;
  const int kwbase = kh * 256 + kq * 8;

  // ---- one-time: weights into registers (as f32x4 bit-buckets of bf16x8).
  // Wr/Wur hi+lo (3-term MFMA split); Wk/Wu hi only (x supplies its own lo term).
  f32x4 WKH[8], WRH[8], WRL[8], WUH[8], WQH[8], WQL[8];
#pragma unroll
  for (int kb = 0; kb < 8; ++kb) {
    union { bf16x8 v; f32x4 f; } kh_, rh_, rl_, uh_, qh_, ql_;
#pragma unroll
    for (int j = 0; j < 8; ++j) {
      const size_t ko = (size_t)(kwbase + kb * 32 + j) * Uc + col;
      { float v = Wk[ko]; kh_.v[j] = (bf16)v; }
      { float v = Wr[ko]; bf16 h0 = (bf16)v; rh_.v[j] = h0; rl_.v[j] = (bf16)(v - (float)h0); }
      { float v = Wu[ko]; uh_.v[j] = (bf16)v; }
      { float v = Wur[ko]; bf16 h0 = (bf16)v; qh_.v[j] = h0; ql_.v[j] = (bf16)(v - (float)h0); }
    }
    WKH[kb] = kh_.f; WRH[kb] = rh_.f; WRL[kb] = rl_.f;
    WUH[kb] = uh_.f; WQH[kb] = qh_.f; WQL[kb] = ql_.f;
  }
  // pin in VGPRs: opaque to the optimizer => no remat/reload inside the loop
#pragma unroll
  for (int kb = 0; kb < 8; ++kb)
    asm volatile("" : "+v"(WKH[kb]), "+v"(WRH[kb]), "+v"(WRL[kb]),
                     "+v"(WUH[kb]), "+v"(WQH[kb]), "+v"(WQL[kb]));
#define WB(arr, kb) __builtin_bit_cast(bf16x8, arr[kb])

  const float brv = br[col], burv = bur[col];

  unsigned* hxg = hx + g * (ROWS * Uc);
  unsigned* gxg = gx + g * (ROWS * Uc);
  unsigned* hxr = hxg + r16 * Uc;
  unsigned* gxr = gxg + r16 * Uc;
  unsigned* flags = ctrs + g * 64;
  const int slot = cw * 4 + w;

  const float* xrow = x + (size_t)(g * ROWS + r16) * Tc * Dc + kwbase;

  float h_keep[4] = {0.f, 0.f, 0.f, 0.f}, f_keep[4];

  f32x4 axk0, axk1, axu0, axu1;

  auto do_x = [&](int t) {
    bf16x8 xhi[8], xlo[8];
    const float* xp = xrow + (size_t)t * Dc;
#pragma unroll
    for (int kb = 0; kb < 8; ++kb) {
      f32x4 a = *(const f32x4*)(xp + kb * 32);
      f32x4 b = *(const f32x4*)(xp + kb * 32 + 4);
#pragma unroll
      for (int j = 0; j < 4; ++j) {
        bf16 h0 = (bf16)a[j]; xhi[kb][j] = h0; xlo[kb][j] = (bf16)(a[j] - (float)h0);
        bf16 h1 = (bf16)b[j]; xhi[kb][4 + j] = h1; xlo[kb][4 + j] = (bf16)(b[j] - (float)h1);
      }
    }
    axk0 = (f32x4){0.f, 0.f, 0.f, 0.f}; axk1 = axk0; axu0 = axk0; axu1 = axk0;
#pragma unroll
    for (int kb = 0; kb < 8; ++kb) {
      axk0 = MFMA16(xhi[kb], WB(WKH, kb), axk0);
      axk1 = MFMA16(xlo[kb], WB(WKH, kb), axk1);
      axu0 = MFMA16(xhi[kb], WB(WUH, kb), axu0);
      axu1 = MFMA16(xlo[kb], WB(WUH, kb), axu1);
    }
  };

  do_x(0);
  unsigned bar = 0;

  for (int t = 0; t < Tc; ++t) {
    // ---- phase 1: a_f = x@Wk (done) + h@Wr
    u32x4 hb[16];
#pragma unroll
    for (int kb = 0; kb < 8; ++kb)
      load8(hxr + kwbase + kb * 32, hb[2 * kb], hb[2 * kb + 1]);
    asm volatile("s_waitcnt vmcnt(0)" ::: "memory");
    __builtin_amdgcn_sched_barrier(0);
    f32x4 r0 = {0.f, 0.f, 0.f, 0.f}, r1 = r0, r2 = r0;
#pragma unroll
    for (int kb = 0; kb < 8; ++kb) {
      bf16x8 fh, fl;
      unpack8(hb[2 * kb], hb[2 * kb + 1], fh, fl);
      r0 = MFMA16(fh, WB(WRH, kb), r0);
      r1 = MFMA16(fl, WB(WRH, kb), r1);
      r2 = MFMA16(fh, WB(WRL, kb), r2);
    }
    if (kh == 1) {
#pragma unroll
      for (int r = 0; r < 4; ++r)
        red[ct][kq * 4 + r][r16] = axk0[r] + axk1[r] + r0[r] + r1[r] + r2[r];
    }
    __syncthreads();
    if (kh == 0) {
#pragma unroll
      for (int r = 0; r < 4; ++r) {
        float af = axk0[r] + axk1[r] + r0[r] + r1[r] + r2[r] +
                   red[ct][kq * 4 + r][r16] + brv;
        float f = __builtin_amdgcn_rcpf(1.f + __expf(-af));
        float gv = h_keep[r] * f;
        f_keep[r] = f;
        __hip_atomic_store(gxg + (kq * 4 + r) * Uc + col, pack2(gv),
                           __ATOMIC_RELAXED, __HIP_MEMORY_SCOPE_AGENT);
      }
    }
    arrive(flags, slot, ++bar);
    waitall(flags, lane, bar);  // g published

    // ---- phase 2: a_h = x@Wu (done) + g@Wur
    u32x4 gb[16];
#pragma unroll
    for (int kb = 0; kb < 8; ++kb)
      load8(gxr + kwbase + kb * 32, gb[2 * kb], gb[2 * kb + 1]);
    asm volatile("s_waitcnt vmcnt(0)" ::: "memory");
    __builtin_amdgcn_sched_barrier(0);
    f32x4 q0 = {0.f, 0.f, 0.f, 0.f}, q1 = q0, q2 = q0;
#pragma unroll
    for (int kb = 0; kb < 8; ++kb) {
      bf16x8 fh, fl;
      unpack8(gb[2 * kb], gb[2 * kb + 1], fh, fl);
      q0 = MFMA16(fh, WB(WQH, kb), q0);
      q1 = MFMA16(fl, WB(WQH, kb), q1);
      q2 = MFMA16(fh, WB(WQL, kb), q2);
    }
    if (kh == 1) {
#pragma unroll
      for (int r = 0; r < 4; ++r)
        red[ct][kq * 4 + r][r16] = axu0[r] + axu1[r] + q0[r] + q1[r] + q2[r];
    }
    __syncthreads();
    if (kh == 0) {
#pragma unroll
      for (int r = 0; r < 4; ++r) {
        float ah = axu0[r] + axu1[r] + q0[r] + q1[r] + q2[r] +
                   red[ct][kq * 4 + r][r16] + burv;
        float e2 = __expf(2.f * ah);
        float hc = 1.f - 2.f * __builtin_amdgcn_rcpf(e2 + 1.f);  // tanh
        float hn = h_keep[r] + f_keep[r] * (hc - h_keep[r]);
        h_keep[r] = hn;
        __hip_atomic_store(hxg + (kq * 4 + r) * Uc + col, pack2(hn),
                           __ATOMIC_RELAXED, __HIP_MEMORY_SCOPE_AGENT);
        if (t == Tc - 1) out[(size_t)(g * ROWS + kq * 4 + r) * Uc + col] = hn;
      }
    }
    arrive(flags, slot, ++bar);
    if (t + 1 < Tc) do_x(t + 1);  // x(t+1) convert + x-MFMAs inside wait window
    waitall(flags, lane, bar);    // h published
  }
}

extern "C" void kernel_launch(void* const* d_in, const int* in_sizes, int n_in,
                              void* d_out, int out_size, void* d_ws, size_t ws_size,
                              hipStream_t stream) {
  const float* x   = (const float*)d_in[0];
  const float* Wk  = (const float*)d_in[1];
  const float* Wr  = (const float*)d_in[2];
  const float* br  = (const float*)d_in[3];
  const float* Wu  = (const float*)d_in[4];
  const float* Wur = (const float*)d_in[5];
  const float* bur = (const float*)d_in[6];
  float* out = (float*)d_out;

  char* ws = (char*)d_ws;
  unsigned* ctrs = (unsigned*)ws;
  unsigned* hx = (unsigned*)(ws + WS_H);
  unsigned* gx = (unsigned*)(ws + WS_G);

  hipMemsetAsync(d_ws, 0, WS_ZERO_BYTES, stream);  // h0 = 0, flags = 0

  hipLaunchKernelGGL(mgu_kernel, dim3(GROUPS * WPG), dim3(256), 0, stream,
                     x, Wk, Wr, br, Wu, Wur, bur, hx, gx, ctrs, out);
}

// Round 4
// 10672.086 us; speedup vs baseline: 2.3256x; 1.2012x over previous
//
#include <hip/hip_runtime.h>

// BasicMGU scan, flag-free dataflow version.
// 4 batch-groups x 16 rows; 16 WGs/group each owning 32 cols; 4 waves/WG each
// owning a K-quarter (128). Exchange h and g=h*f through IF-coherent slots as
// (epoch16|bf16hi),(epoch16|bf16lo) dword pairs. Consumers poll the DATA until
// all epoch tags match -- no flags, no store-ack drains, no barriers at all.
// Weights register-resident (bf16 hi/lo, 3-term MFMA split on recurrent mats).

typedef __bf16 bf16;
typedef __attribute__((ext_vector_type(8))) __bf16 bf16x8;
typedef __attribute__((ext_vector_type(4))) float f32x4;
typedef __attribute__((ext_vector_type(4))) unsigned u32x4;
typedef __attribute__((ext_vector_type(2))) unsigned u32x2;

#define MFMA16(a, b, c) __builtin_amdgcn_mfma_f32_16x16x32_bf16((a), (b), (c), 0, 0, 0)
#define WB(q) __builtin_bit_cast(bf16x8, q)

constexpr int Tc = 1024, Dc = 512, Uc = 512;
constexpr int GROUPS = 4, ROWS = 16, WPG = 16;

// ws: H[4][16][512][2] u32 at 0 (256KB); G same at +256KB. Zero both per call.
constexpr size_t WS_G_OFF = (size_t)GROUPS * ROWS * Uc * 2 * 4;  // 262144
constexpr size_t WS_ZERO = 2 * WS_G_OFF;                          // 524288

// 16-quad tagged load: one lane's 32 values (64 dwords). Per kb (4): 16
// contiguous dwords at byte offset kb*256, as 4 dwordx4. sc0 sc1 => served at
// the IF coherence point, always fresh.
__device__ inline void load16q(const unsigned* p, u32x4 b[16]) {
  asm volatile(
      "global_load_dwordx4 %0,  %16, off sc0 sc1\n\t"
      "global_load_dwordx4 %1,  %16, off offset:16 sc0 sc1\n\t"
      "global_load_dwordx4 %2,  %16, off offset:32 sc0 sc1\n\t"
      "global_load_dwordx4 %3,  %16, off offset:48 sc0 sc1\n\t"
      "global_load_dwordx4 %4,  %16, off offset:256 sc0 sc1\n\t"
      "global_load_dwordx4 %5,  %16, off offset:272 sc0 sc1\n\t"
      "global_load_dwordx4 %6,  %16, off offset:288 sc0 sc1\n\t"
      "global_load_dwordx4 %7,  %16, off offset:304 sc0 sc1\n\t"
      "global_load_dwordx4 %8,  %16, off offset:512 sc0 sc1\n\t"
      "global_load_dwordx4 %9,  %16, off offset:528 sc0 sc1\n\t"
      "global_load_dwordx4 %10, %16, off offset:544 sc0 sc1\n\t"
      "global_load_dwordx4 %11, %16, off offset:560 sc0 sc1\n\t"
      "global_load_dwordx4 %12, %16, off offset:768 sc0 sc1\n\t"
      "global_load_dwordx4 %13, %16, off offset:784 sc0 sc1\n\t"
      "global_load_dwordx4 %14, %16, off offset:800 sc0 sc1\n\t"
      "global_load_dwordx4 %15, %16, off offset:816 sc0 sc1"
      : "=&v"(b[0]), "=&v"(b[1]), "=&v"(b[2]), "=&v"(b[3]),
        "=&v"(b[4]), "=&v"(b[5]), "=&v"(b[6]), "=&v"(b[7]),
        "=&v"(b[8]), "=&v"(b[9]), "=&v"(b[10]), "=&v"(b[11]),
        "=&v"(b[12]), "=&v"(b[13]), "=&v"(b[14]), "=&v"(b[15])
      : "v"(p) : "memory");
}

__device__ inline bool freshq(const u32x4* b, unsigned tag) {
  unsigned acc = 0;
#pragma unroll
  for (int i = 0; i < 16; ++i) {
    u32x4 v = b[i];
    acc |= (v[0] ^ tag) | (v[1] ^ tag) | (v[2] ^ tag) | (v[3] ^ tag);
  }
  return (acc & 0xFFFF0000u) == 0;
}

__device__ inline void pollq(const unsigned* p, unsigned tag, u32x4 b[16]) {
  for (;;) {
    load16q(p, b);
    asm volatile("s_waitcnt vmcnt(0)" ::: "memory");
    __builtin_amdgcn_sched_barrier(0);  // rule 18: nothing hoists above the wait
    if (__ballot(!freshq(b, tag)) == 0) break;
  }
}

// quad jj of one kb holds [hi(2jj), lo(2jj), hi(2jj+1), lo(2jj+1)]
__device__ inline void mk8(const u32x4* q, bf16x8& fh, bf16x8& fl) {
  union { unsigned d[4]; bf16x8 v; } H, L;
#pragma unroll
  for (int jj = 0; jj < 4; ++jj) {
    H.d[jj] = (q[jj][0] & 0xFFFFu) | (q[jj][2] << 16);
    L.d[jj] = (q[jj][1] & 0xFFFFu) | (q[jj][3] << 16);
  }
  fh = H.v;
  fl = L.v;
}

__device__ inline void store_pair(unsigned* p, unsigned tag, float v) {
  bf16 hi = (bf16)v;
  bf16 lo = (bf16)(v - (float)hi);
  u32x2 d;
  d[0] = tag | (unsigned)__builtin_bit_cast(unsigned short, hi);
  d[1] = tag | (unsigned)__builtin_bit_cast(unsigned short, lo);
  asm volatile("global_store_dwordx2 %0, %1, off sc0 sc1" ::"v"(p), "v"(d) : "memory");
}

__global__ __launch_bounds__(256, 1)
void mgu_kernel(const float* __restrict__ x,
                const float* __restrict__ Wk, const float* __restrict__ Wr,
                const float* __restrict__ br,
                const float* __restrict__ Wu, const float* __restrict__ Wur,
                const float* __restrict__ bur,
                unsigned* __restrict__ H, unsigned* __restrict__ G,
                float* __restrict__ out) {
  __shared__ float red[2][4][2][16][16];  // [phase][wave][ct][row][col16]

  const int wg = blockIdx.x;
  const int g = wg >> 4, cw = wg & 15, c0 = cw * 32;
  const int tid = threadIdx.x, w = tid >> 6, lane = tid & 63;
  const int dcol = lane & 15, kq = lane >> 4;     // A-row / D-col = dcol
  const int kbase = w * 128 + kq * 8;             // wave = K-quarter

  // ---- weights into registers: B-frag W[k=kbase+kb*32+j][c0+ct*16+dcol].
  // Wr/Wur hi+lo (3-term); Wk/Wu hi only (x supplies its own lo term).
  f32x4 WKH[2][4], WRH[2][4], WRL[2][4], WUH[2][4], WQH[2][4], WQL[2][4];
#pragma unroll
  for (int ct = 0; ct < 2; ++ct) {
    const int col = c0 + ct * 16 + dcol;
#pragma unroll
    for (int kb = 0; kb < 4; ++kb) {
      union { bf16x8 v; f32x4 f; } a_, b_, c_, d_, e_, q_;
#pragma unroll
      for (int j = 0; j < 8; ++j) {
        const size_t ko = (size_t)(kbase + kb * 32 + j) * Uc + col;
        { float v = Wk[ko]; a_.v[j] = (bf16)v; }
        { float v = Wr[ko]; bf16 h0 = (bf16)v; b_.v[j] = h0; c_.v[j] = (bf16)(v - (float)h0); }
        { float v = Wu[ko]; d_.v[j] = (bf16)v; }
        { float v = Wur[ko]; bf16 h0 = (bf16)v; e_.v[j] = h0; q_.v[j] = (bf16)(v - (float)h0); }
      }
      WKH[ct][kb] = a_.f; WRH[ct][kb] = b_.f; WRL[ct][kb] = c_.f;
      WUH[ct][kb] = d_.f; WQH[ct][kb] = e_.f; WQL[ct][kb] = q_.f;
    }
  }
#pragma unroll
  for (int ct = 0; ct < 2; ++ct)
#pragma unroll
    for (int kb = 0; kb < 4; ++kb)
      asm volatile("" : "+v"(WKH[ct][kb]), "+v"(WRH[ct][kb]), "+v"(WRL[ct][kb]),
                       "+v"(WUH[ct][kb]), "+v"(WQH[ct][kb]), "+v"(WQL[ct][kb]));

  // ---- finalizer assignment: wave w owns rows 4w..4w+3; lane -> 2 outputs
  const int sub = lane >> 5, colL = lane & 31;
  const int fct = colL >> 4, fc16 = colL & 15;
  const float brv = br[c0 + colL], burv = bur[c0 + colL];
  const int row0 = 4 * w + sub, row1 = 4 * w + 2 + sub;

  // exchange pointers
  const unsigned* Hld = H + ((size_t)(g * ROWS + dcol) * Uc + kbase) * 2;
  const unsigned* Gld = G + ((size_t)(g * ROWS + dcol) * Uc + kbase) * 2;
  unsigned* Gs0 = G + ((size_t)(g * ROWS + row0) * Uc + c0 + colL) * 2;
  unsigned* Gs1 = G + ((size_t)(g * ROWS + row1) * Uc + c0 + colL) * 2;
  unsigned* Hs0 = H + ((size_t)(g * ROWS + row0) * Uc + c0 + colL) * 2;
  unsigned* Hs1 = H + ((size_t)(g * ROWS + row1) * Uc + c0 + colL) * 2;

  const float* xptr = x + (size_t)(g * ROWS + dcol) * Tc * Dc + kbase;

  float h_keep[2] = {0.f, 0.f}, f_keep[2] = {0.f, 0.f};
  f32x4 axk[2], axu[2];

  auto do_x = [&](int t) {
    const float* xp = xptr + (size_t)t * Dc;
    bf16x8 xh[4], xl[4];
#pragma unroll
    for (int kb = 0; kb < 4; ++kb) {
      f32x4 a = *(const f32x4*)(xp + kb * 32);
      f32x4 b = *(const f32x4*)(xp + kb * 32 + 4);
#pragma unroll
      for (int j = 0; j < 4; ++j) {
        bf16 h0 = (bf16)a[j]; xh[kb][j] = h0; xl[kb][j] = (bf16)(a[j] - (float)h0);
        bf16 h1 = (bf16)b[j]; xh[kb][4 + j] = h1; xl[kb][4 + j] = (bf16)(b[j] - (float)h1);
      }
    }
#pragma unroll
    for (int ct = 0; ct < 2; ++ct) {
      f32x4 k_ = {0.f, 0.f, 0.f, 0.f}, u_ = k_;
#pragma unroll
      for (int kb = 0; kb < 4; ++kb) {
        k_ = MFMA16(xh[kb], WB(WKH[ct][kb]), k_);
        k_ = MFMA16(xl[kb], WB(WKH[ct][kb]), k_);
        u_ = MFMA16(xh[kb], WB(WUH[ct][kb]), u_);
        u_ = MFMA16(xl[kb], WB(WUH[ct][kb]), u_);
      }
      axk[ct] = k_;
      axu[ct] = u_;
    }
  };

  do_x(0);

  for (int t = 0; t < Tc; ++t) {
    const unsigned tag0 = (unsigned)t << 16, tag1 = (unsigned)(t + 1) << 16;
    u32x4 b[16];

    // ---- phase 1: a_f = x@Wk (done) + h@Wr; h polled in-place
    pollq(Hld, tag0, b);
    {
      bf16x8 fh[4], fl[4];
#pragma unroll
      for (int kb = 0; kb < 4; ++kb) mk8(&b[kb * 4], fh[kb], fl[kb]);
#pragma unroll
      for (int ct = 0; ct < 2; ++ct) {
        f32x4 r = axk[ct];
#pragma unroll
        for (int kb = 0; kb < 4; ++kb) {
          r = MFMA16(fh[kb], WB(WRH[ct][kb]), r);
          r = MFMA16(fl[kb], WB(WRH[ct][kb]), r);
          r = MFMA16(fh[kb], WB(WRL[ct][kb]), r);
        }
#pragma unroll
        for (int i = 0; i < 4; ++i) red[0][w][ct][kq * 4 + i][dcol] = r[i];
      }
    }
    __syncthreads();
    {
      float af0 = red[0][0][fct][row0][fc16] + red[0][1][fct][row0][fc16] +
                  red[0][2][fct][row0][fc16] + red[0][3][fct][row0][fc16] + brv;
      float af1 = red[0][0][fct][row1][fc16] + red[0][1][fct][row1][fc16] +
                  red[0][2][fct][row1][fc16] + red[0][3][fct][row1][fc16] + brv;
      float f0 = __builtin_amdgcn_rcpf(1.f + __expf(-af0));
      float f1 = __builtin_amdgcn_rcpf(1.f + __expf(-af1));
      f_keep[0] = f0; f_keep[1] = f1;
      store_pair(Gs0, tag1, h_keep[0] * f0);  // g = h.*f, exact f32 product
      store_pair(Gs1, tag1, h_keep[1] * f1);
    }

    // ---- phase 2: a_h = x@Wu (done) + g@Wur; g polled in-place
    pollq(Gld, tag1, b);
    {
      bf16x8 gh[4], gl[4];
#pragma unroll
      for (int kb = 0; kb < 4; ++kb) mk8(&b[kb * 4], gh[kb], gl[kb]);
#pragma unroll
      for (int ct = 0; ct < 2; ++ct) {
        f32x4 q = axu[ct];
#pragma unroll
        for (int kb = 0; kb < 4; ++kb) {
          q = MFMA16(gh[kb], WB(WQH[ct][kb]), q);
          q = MFMA16(gl[kb], WB(WQH[ct][kb]), q);
          q = MFMA16(gh[kb], WB(WQL[ct][kb]), q);
        }
#pragma unroll
        for (int i = 0; i < 4; ++i) red[1][w][ct][kq * 4 + i][dcol] = q[i];
      }
    }
    __syncthreads();
    {
      float ah0 = red[1][0][fct][row0][fc16] + red[1][1][fct][row0][fc16] +
                  red[1][2][fct][row0][fc16] + red[1][3][fct][row0][fc16] + burv;
      float ah1 = red[1][0][fct][row1][fc16] + red[1][1][fct][row1][fc16] +
                  red[1][2][fct][row1][fc16] + red[1][3][fct][row1][fc16] + burv;
      float e20 = __expf(2.f * ah0), e21 = __expf(2.f * ah1);
      float hc0 = 1.f - 2.f * __builtin_amdgcn_rcpf(e20 + 1.f);  // tanh
      float hc1 = 1.f - 2.f * __builtin_amdgcn_rcpf(e21 + 1.f);
      float hn0 = h_keep[0] + f_keep[0] * (hc0 - h_keep[0]);
      float hn1 = h_keep[1] + f_keep[1] * (hc1 - h_keep[1]);
      h_keep[0] = hn0; h_keep[1] = hn1;
      store_pair(Hs0, tag1, hn0);
      store_pair(Hs1, tag1, hn1);
      if (t == Tc - 1) {
        out[(size_t)(g * ROWS + row0) * Uc + c0 + colL] = hn0;
        out[(size_t)(g * ROWS + row1) * Uc + c0 + colL] = hn1;
      }
    }
    if (t + 1 < Tc) do_x(t + 1);  // x(t+1) loads + MFMAs overlap peers' phase-1
  }
}

extern "C" void kernel_launch(void* const* d_in, const int* in_sizes, int n_in,
                              void* d_out, int out_size, void* d_ws, size_t ws_size,
                              hipStream_t stream) {
  const float* x   = (const float*)d_in[0];
  const float* Wk  = (const float*)d_in[1];
  const float* Wr  = (const float*)d_in[2];
  const float* br  = (const float*)d_in[3];
  const float* Wu  = (const float*)d_in[4];
  const float* Wur = (const float*)d_in[5];
  const float* bur = (const float*)d_in[6];
  float* out = (float*)d_out;

  char* ws = (char*)d_ws;
  unsigned* H = (unsigned*)ws;
  unsigned* G = (unsigned*)(ws + WS_G_OFF);

  // zero h0 (epoch 0 | 0.0) and clear all stale epochs (deterministic per call)
  hipMemsetAsync(d_ws, 0, WS_ZERO, stream);

  hipLaunchKernelGGL(mgu_kernel, dim3(GROUPS * WPG), dim3(256), 0, stream,
                     x, Wk, Wr, br, Wu, Wur, bur, H, G, out);
}